// Round 4
// baseline (260.158 us; speedup 1.0000x reference)
//
#include <hip/hip_runtime.h>
#include <hip/hip_bf16.h>

typedef __attribute__((ext_vector_type(8))) short bf16x8;
typedef __attribute__((ext_vector_type(4))) float f32x4;

#define NB 8
#define NN 2048
#define DM 512
#define DF 1024

__device__ __forceinline__ ushort f2b(float f) {
  union { __hip_bfloat16 h; ushort u; } c;
  c.h = __float2bfloat16(f);
  return c.u;
}
__device__ __forceinline__ float b2f(ushort u) {
  union { ushort u; __hip_bfloat16 h; } c;
  c.u = u;
  return __bfloat162float(c.h);
}

typedef __attribute__((address_space(1))) const void gvoid_t;
typedef __attribute__((address_space(3))) void svoid_t;
__device__ __forceinline__ void gload16(const void* g, void* s) {
  __builtin_amdgcn_global_load_lds((gvoid_t*)g, (svoid_t*)s, 16, 0, 0);
}

// ---------------- NT GEMM core (unchanged, verified) ----------------
__device__ __forceinline__ void gemm_core_128(
    const ushort* __restrict__ A, const ushort* __restrict__ B,
    int K, int brow, int bcol, f32x4 (&acc)[4][4], ushort* smem)
{
  ushort* As = smem;
  ushort* Bs = smem + 128 * 64;
  const int tid = threadIdx.x;
  const int w = tid >> 6;
  const int l = tid & 63;
  const int sr = (w << 3) + (l >> 3);
  const int sc = (((l & 7) ^ (l >> 3)) << 3);
  char* AsB = (char*)As;
  char* BsB = (char*)Bs;
  const int fr = l & 15;
  const int arow = ((w >> 1) << 6) + fr;
  const int brw  = ((w & 1) << 6) + fr;

#pragma unroll
  for (int m = 0; m < 4; m++)
#pragma unroll
    for (int n = 0; n < 4; n++)
      acc[m][n] = (f32x4){0.f, 0.f, 0.f, 0.f};

  const ushort* Ap = A + (long)(brow + sr) * K + sc;
  const ushort* Bp = B + (long)(bcol + sr) * K + sc;
  const int nkt = K >> 6;
  for (int kt = 0; kt < nkt; ++kt) {
#pragma unroll
    for (int i = 0; i < 4; i++) {
      gload16(Ap + (long)i * 32 * K, AsB + i * 4096 + (w << 10));
      gload16(Bp + (long)i * 32 * K, BsB + i * 4096 + (w << 10));
    }
    Ap += 64; Bp += 64;
    __syncthreads();
#pragma unroll
    for (int kk = 0; kk < 2; kk++) {
      const int cx = ((((kk << 2) + (l >> 4)) ^ (l & 7)) << 4);
      bf16x8 a[4], b[4];
#pragma unroll
      for (int m = 0; m < 4; m++)
        a[m] = *(const bf16x8*)(AsB + (arow + m * 16) * 128 + cx);
#pragma unroll
      for (int n = 0; n < 4; n++)
        b[n] = *(const bf16x8*)(BsB + (brw + n * 16) * 128 + cx);
#pragma unroll
      for (int m = 0; m < 4; m++)
#pragma unroll
        for (int n = 0; n < 4; n++)
          acc[m][n] = __builtin_amdgcn_mfma_f32_16x16x32_bf16(a[m], b[n], acc[m][n], 0, 0, 0);
    }
    __syncthreads();
  }
}

__device__ __forceinline__ void acc_to_lds_bf16(f32x4 (&acc)[4][4], ushort* smem) {
  const int tid = threadIdx.x, w = tid >> 6, l = tid & 63;
  const int r0l = ((w >> 1) << 6) + ((l >> 4) << 2);
  const int c0l = ((w & 1) << 6) + (l & 15);
#pragma unroll
  for (int n = 0; n < 4; n++)
#pragma unroll
    for (int m = 0; m < 4; m++)
#pragma unroll
      for (int j = 0; j < 4; j++)
        smem[(r0l + m * 16 + j) * 128 + (c0l + n * 16)] = f2b(acc[m][n][j]);
}

// ---------------- kernels ----------------

__global__ __launch_bounds__(256) void k_cvt(const float* __restrict__ in,
                                             ushort* __restrict__ out) {
  const long i = ((long)blockIdx.x * 256 + threadIdx.x) << 2;
  const float4 v = *(const float4*)(in + i);
  ushort4 o;
  o.x = f2b(v.x); o.y = f2b(v.y); o.z = f2b(v.z); o.w = f2b(v.w);
  *(ushort4*)(out + i) = o;
}

__device__ __forceinline__ float ld2f(const float* p, long i) { return p[i]; }
__device__ __forceinline__ float ld2f(const __hip_bfloat16* p, long i) { return __bfloat162float(p[i]); }

template <typename TIN>
__global__ __launch_bounds__(256) void k_tr(const TIN* __restrict__ in, ushort* __restrict__ out,
                                            int R, int C, long inB, long outB) {
  __shared__ float t[32][33];
  const long b = blockIdx.z;
  const TIN* ip = in + b * inB;
  ushort* op = out + b * outB;
  const int c0 = blockIdx.x << 5, r0 = blockIdx.y << 5;
  const int tx = threadIdx.x & 31, ty = threadIdx.x >> 5;
#pragma unroll
  for (int j = 0; j < 32; j += 8)
    t[ty + j][tx] = ld2f(ip, (long)(r0 + ty + j) * C + (c0 + tx));
  __syncthreads();
#pragma unroll
  for (int j = 0; j < 32; j += 8)
    op[(long)(c0 + ty + j) * R + (r0 + tx)] = f2b(t[tx][ty + j]);
}

__global__ __launch_bounds__(256) void k_gemm1(const ushort* __restrict__ xb,
                                               const ushort* __restrict__ w1t,
                                               const float* __restrict__ b1,
                                               ushort* __restrict__ hb) {
  __shared__ ushort smem[128 * 128];
  f32x4 acc[4][4];
  const int brow = blockIdx.x << 7, bcol = blockIdx.y << 7;
  gemm_core_128(xb, w1t, DM, brow, bcol, acc, smem);
  const int tid = threadIdx.x, w = tid >> 6, l = tid & 63;
  const int c0l = ((w & 1) << 6) + (l & 15);
#pragma unroll
  for (int n = 0; n < 4; n++) {
    const float bias = b1[bcol + c0l + n * 16];
#pragma unroll
    for (int m = 0; m < 4; m++)
#pragma unroll
      for (int j = 0; j < 4; j++) {
        float v = acc[m][n][j] + bias;
        acc[m][n][j] = v > 0.f ? v : 0.f;
      }
  }
  acc_to_lds_bf16(acc, smem);
  __syncthreads();
  const int rb = tid >> 4, cb = tid & 15;
#pragma unroll
  for (int i = 0; i < 8; i++) {
    const int row = i * 16 + rb;
    bf16x8 s = *(const bf16x8*)(smem + row * 128 + cb * 8);
    *(bf16x8*)(hb + (long)(brow + row) * DF + bcol + cb * 8) = s;
  }
}

__global__ __launch_bounds__(256) void k_gemm2(const ushort* __restrict__ hb,
                                               const ushort* __restrict__ w2t,
                                               const float* __restrict__ b2,
                                               ushort* __restrict__ kb,
                                               ushort* __restrict__ qb,
                                               ushort* __restrict__ vb) {
  __shared__ ushort smem[128 * 128];
  f32x4 acc[4][4];
  const int brow = blockIdx.x << 7, bcol = blockIdx.y << 7;
  gemm_core_128(hb, w2t, DF, brow, bcol, acc, smem);
  const int seg = bcol >> 9;
  ushort* dst = (seg == 0) ? kb : ((seg == 1) ? qb : vb);
  const float sc = (seg == 1) ? 0.04419417382415922f : 1.0f;  // 1/sqrt(512) into q
  const int tid = threadIdx.x, w = tid >> 6, l = tid & 63;
  const int c0l = ((w & 1) << 6) + (l & 15);
#pragma unroll
  for (int n = 0; n < 4; n++) {
    const float bias = b2[bcol + c0l + n * 16];
#pragma unroll
    for (int m = 0; m < 4; m++)
#pragma unroll
      for (int j = 0; j < 4; j++)
        acc[m][n][j] = (acc[m][n][j] + bias) * sc;
  }
  acc_to_lds_bf16(acc, smem);
  __syncthreads();
  const int rb = tid >> 4, cb = tid & 15;
  const int clb = bcol - (seg << 9);
#pragma unroll
  for (int i = 0; i < 8; i++) {
    const int row = i * 16 + rb;
    bf16x8 s = *(const bf16x8*)(smem + row * 128 + cb * 8);
    *(bf16x8*)(dst + (long)(brow + row) * DM + clb + cb * 8) = s;
  }
}

// ---------------- fused attention: O = (q.k^T [pre-scaled] * mask) @ v ----------------
// Block: 512 thr / 8 waves, q-tile = 64 rows, full D=512 output in regs.
// Per kv-tile (128): S (8 waves x 16-col strip), mask from global (issued early),
// P -> LDS bf16 (16-slot XOR swizzle), PV accumulates O (16 f32x4/thread).
// batch = blockIdx.x & 7 pins each batch's k/v to one XCD's L2.
__global__ __launch_bounds__(512, 2) void k_attn(const ushort* __restrict__ qb,
                                                 const ushort* __restrict__ kb,
                                                 const ushort* __restrict__ vtb,
                                                 const float* __restrict__ mask,
                                                 float* __restrict__ out) {
  __shared__ ushort smem[73728];  // 144 KB
  char* QsB = (char*)smem;                 // [8 chunks][64 rows][128 B]
  char* KsB = (char*)smem + 65536;         // [2 sub][128 rows][128 B]
  char* VsB = (char*)smem + 65536 + 32768; // [2 sub][64 rows][256 B]
  char* PsB = (char*)smem + 65536 + 65536; // [64 rows][256 B]

  const int tid = threadIdx.x, w = tid >> 6, l = tid & 63;
  const int fr = l & 15;
  const int batch = blockIdx.x & 7;
  const int qrow0 = (blockIdx.x >> 3) << 6;
  const ushort* qp = qb + (long)batch * NN * DM;
  const ushort* kp = kb + (long)batch * NN * DM;
  const ushort* vp = vtb + (long)batch * DM * NN;
  const float* mp = mask + (long)batch * NN * NN;
  float* op = out + (long)batch * NN * DM;

  f32x4 acc[8][2];
#pragma unroll
  for (int dc = 0; dc < 8; dc++)
#pragma unroll
    for (int f = 0; f < 2; f++)
      acc[dc][f] = (f32x4){0.f, 0.f, 0.f, 0.f};

  // stage Q resident: 8 chunk-tiles [64][64], m97 layout+swizzle
  {
    const int r = (w << 3) + (l >> 3);
    const int scol = ((l & 7) ^ (l >> 3)) << 3;
#pragma unroll
    for (int i = 0; i < 8; i++)
      gload16(qp + (long)(qrow0 + r) * DM + i * 64 + scol, QsB + i * 8192 + (w << 10));
  }

  for (int t = 0; t < 16; ++t) {
    const int kv0 = t << 7;
    // mask regs (issued before compute; overlap)
    float mreg[4][4];
#pragma unroll
    for (int m = 0; m < 4; m++)
#pragma unroll
      for (int j = 0; j < 4; j++)
        mreg[m][j] = mp[(long)(qrow0 + m * 16 + ((l >> 4) << 2) + j) * NN + kv0 + (w << 4) + fr];

    f32x4 sacc[4];
#pragma unroll
    for (int m = 0; m < 4; m++) sacc[m] = (f32x4){0.f, 0.f, 0.f, 0.f};

    // ---- S phase: 4 barrier-pairs, each staging 2 d-chunks of K ----
#pragma unroll
    for (int dch = 0; dch < 4; ++dch) {
      __syncthreads();  // prev readers of Ks (or Ps/Vs at dch==0) done
#pragma unroll
      for (int i = 0; i < 4; ++i) {
        const int sub = i >> 1;
        const int r = ((w << 1) + (i & 1)) * 8 + (l >> 3);
        const int scol = ((l & 7) ^ (l >> 3)) << 3;
        gload16(kp + (long)(kv0 + r) * DM + ((dch << 1) + sub) * 64 + scol,
                KsB + sub * 16384 + (((w << 1) + (i & 1)) << 10));
      }
      __syncthreads();  // staging complete
#pragma unroll
      for (int sub = 0; sub < 2; ++sub) {
        const int dc = (dch << 1) + sub;
#pragma unroll
        for (int kk = 0; kk < 2; ++kk) {
          const int cx = (((kk << 2) + (l >> 4)) ^ (l & 7)) << 4;
          bf16x8 bfr = *(const bf16x8*)(KsB + sub * 16384 + ((w << 4) + fr) * 128 + cx);
#pragma unroll
          for (int m = 0; m < 4; m++) {
            bf16x8 a = *(const bf16x8*)(QsB + dc * 8192 + ((m << 4) + fr) * 128 + cx);
            sacc[m] = __builtin_amdgcn_mfma_f32_16x16x32_bf16(a, bfr, sacc[m], 0, 0, 0);
          }
        }
      }
    }

    // ---- P = S * mask -> LDS (bf16), 16-slot XOR swizzle (rows are 256 B) ----
#pragma unroll
    for (int m = 0; m < 4; m++)
#pragma unroll
      for (int j = 0; j < 4; j++) {
        const int row = (m << 4) + ((l >> 4) << 2) + j;
        const int ch = (((w << 1) + ((l >> 3) & 1)) ^ (row & 15));
        *(ushort*)(PsB + row * 256 + (ch << 4) + ((l & 7) << 1)) = f2b(sacc[m][j] * mreg[m][j]);
      }

    // ---- PV phase: 4 barrier-pairs, each staging 2 d-chunks of v^T ----
#pragma unroll
    for (int dch = 0; dch < 4; ++dch) {
      __syncthreads();  // dch==0: Ps visible; all: prev Vs readers done
#pragma unroll
      for (int i = 0; i < 4; ++i) {
        const int sub = i >> 1;
        const int r = ((w << 1) + (i & 1)) * 4 + (l >> 4);
        const int scol = ((l & 15) ^ (r & 15)) << 3;
        gload16(vp + (long)(((dch << 1) + sub) * 64 + r) * NN + kv0 + scol,
                VsB + sub * 16384 + (((w << 1) + (i & 1)) << 10));
      }
      __syncthreads();
#pragma unroll
      for (int sub = 0; sub < 2; ++sub) {
        const int dc = (dch << 1) + sub;
#pragma unroll
        for (int f = 0; f < 2; ++f) {
          const int m = ((w >> 2) << 1) + f;
          f32x4 o = acc[dc][f];
#pragma unroll
          for (int ks = 0; ks < 4; ++ks) {
            const int cxp = (((ks << 2) + (l >> 4)) ^ (l & 15)) << 4;
            bf16x8 pa = *(const bf16x8*)(PsB + ((m << 4) + fr) * 256 + cxp);
            bf16x8 vb_ = *(const bf16x8*)(VsB + sub * 16384 + (((w & 3) << 4) + fr) * 256 + cxp);
            o = __builtin_amdgcn_mfma_f32_16x16x32_bf16(pa, vb_, o, 0, 0, 0);
          }
          acc[dc][f] = o;
        }
      }
    }
  }

  // ---- epilogue: write O (fp32) ----
#pragma unroll
  for (int dc = 0; dc < 8; dc++)
#pragma unroll
    for (int f = 0; f < 2; f++) {
      const int m = ((w >> 2) << 1) + f;
#pragma unroll
      for (int j = 0; j < 4; j++) {
        const int row = qrow0 + (m << 4) + ((l >> 4) << 2) + j;
        const int col = (dc << 6) + ((w & 3) << 4) + fr;
        op[(long)row * DM + col] = acc[dc][f][j];
      }
    }
}

// ---------------- launch ----------------
extern "C" void kernel_launch(void* const* d_in, const int* in_sizes, int n_in,
                              void* d_out, int out_size, void* d_ws, size_t ws_size,
                              hipStream_t stream) {
  const float* x    = (const float*)d_in[0];
  const float* mask = (const float*)d_in[1];
  const float* W1   = (const float*)d_in[2];
  const float* b1   = (const float*)d_in[3];
  const float* W2   = (const float*)d_in[4];
  const float* b2   = (const float*)d_in[5];
  float* out = (float*)d_out;

  char* ws = (char*)d_ws;
  size_t off = 0;
  auto alloc = [&](size_t n) { char* p = ws + off; off += (n + 255) & ~(size_t)255; return p; };
  ushort* xb  = (ushort*)alloc((size_t)NB * NN * DM * 2);
  ushort* hb  = (ushort*)alloc((size_t)NB * NN * DF * 2);
  ushort* w1t = (ushort*)alloc((size_t)DF * DM * 2);
  ushort* w2t = (ushort*)alloc((size_t)3 * DM * DF * 2);
  ushort* kb  = (ushort*)alloc((size_t)NB * NN * DM * 2);
  ushort* qb  = (ushort*)alloc((size_t)NB * NN * DM * 2);
  ushort* vb  = (ushort*)alloc((size_t)NB * NN * DM * 2);
  ushort* vtb = (ushort*)alloc((size_t)NB * NN * DM * 2);

  // x -> bf16
  k_cvt<<<dim3(8192), dim3(256), 0, stream>>>(x, xb);
  // W1 -> w1t ; W2 -> w2t
  k_tr<float><<<dim3(DF / 32, DM / 32, 1), dim3(256), 0, stream>>>(W1, w1t, DM, DF, 0, 0);
  k_tr<float><<<dim3(3 * DM / 32, DF / 32, 1), dim3(256), 0, stream>>>(W2, w2t, DF, 3 * DM, 0, 0);
  // h = relu(x@W1+b1)
  k_gemm1<<<dim3(NB * NN / 128, DF / 128), dim3(256), 0, stream>>>(xb, w1t, b1, hb);
  // kqv = h@W2+b2 (q pre-scaled)
  k_gemm2<<<dim3(NB * NN / 128, 3 * DM / 128), dim3(256), 0, stream>>>(hb, w2t, b2, kb, qb, vb);
  // v -> v^T per batch
  k_tr<__hip_bfloat16><<<dim3(DM / 32, NN / 32, NB), dim3(256), 0, stream>>>(
      (const __hip_bfloat16*)vb, vtb, NN, DM, (long)NN * DM, (long)DM * NN);
  // fused attention: 256 blocks (8 batches x 32 q-tiles), batch pinned to XCD
  k_attn<<<dim3(256), dim3(512), 0, stream>>>(qb, kb, vtb, mask, out);
}

// Round 5
// 221.080 us; speedup vs baseline: 1.1768x; 1.1768x over previous
//
#include <hip/hip_runtime.h>
#include <hip/hip_bf16.h>

typedef __attribute__((ext_vector_type(8))) short bf16x8;
typedef __attribute__((ext_vector_type(4))) float f32x4;

#define NB 8
#define NN 2048
#define DM 512
#define DF 1024

__device__ __forceinline__ ushort f2b(float f) {
  union { __hip_bfloat16 h; ushort u; } c;
  c.h = __float2bfloat16(f);
  return c.u;
}
__device__ __forceinline__ float b2f(ushort u) {
  union { ushort u; __hip_bfloat16 h; } c;
  c.u = u;
  return __bfloat162float(c.h);
}

typedef __attribute__((address_space(1))) const void gvoid_t;
typedef __attribute__((address_space(3))) void svoid_t;
__device__ __forceinline__ void gload16(const void* g, void* s) {
  __builtin_amdgcn_global_load_lds((gvoid_t*)g, (svoid_t*)s, 16, 0, 0);
}

// ---------------- NT GEMM core, double-buffered (T3-minimum 2-phase) -------
// C[128x128] = A[128 rows of K] * B[128 rows of K]^T ; bf16 in, fp32 acc.
// BK=64. XOR swizzle on global source + ds_read addr (both-sides, rule 21).
// smem: 128*256 ushort (64 KB): [A0 16K][B0 16K][A1 16K][B1 16K].
// Schedule per 2 tiles: {stage(next) -> compute(cur) -> sync} -- the vmcnt(0)
// drain inside __syncthreads lands AFTER compute, hiding load latency.
// Requires K % 128 == 0. Ends with __syncthreads() -> caller may reuse smem.
__device__ __forceinline__ void gemm_core_128(
    const ushort* __restrict__ A, const ushort* __restrict__ B,
    int K, int brow, int bcol, f32x4 (&acc)[4][4], ushort* smem)
{
  const int tid = threadIdx.x;
  const int w = tid >> 6, l = tid & 63;
  const int sr = (w << 3) + (l >> 3);
  const int sc = (((l & 7) ^ (l >> 3)) << 3);   // swizzled source chunk
  const int fr = l & 15;
  const int arow = ((w >> 1) << 6) + fr;
  const int brw  = ((w & 1) << 6) + fr;
  char* base = (char*)smem;
  char* A0 = base;          char* B0 = base + 16384;
  char* A1 = base + 32768;  char* B1 = base + 49152;

#pragma unroll
  for (int m = 0; m < 4; m++)
#pragma unroll
    for (int n = 0; n < 4; n++)
      acc[m][n] = (f32x4){0.f, 0.f, 0.f, 0.f};

  const ushort* Ap = A + (long)(brow + sr) * K + sc;
  const ushort* Bp = B + (long)(bcol + sr) * K + sc;
  const int nkt = K >> 6;  // even

  auto stage = [&](char* Ad, char* Bd, int kt) {
#pragma unroll
    for (int i = 0; i < 4; i++) {
      gload16(Ap + (long)i * 32 * K + kt * 64, Ad + i * 4096 + (w << 10));
      gload16(Bp + (long)i * 32 * K + kt * 64, Bd + i * 4096 + (w << 10));
    }
  };
  auto compute = [&](const char* As_, const char* Bs_) {
#pragma unroll
    for (int kk = 0; kk < 2; kk++) {
      const int cx = ((((kk << 2) + (l >> 4)) ^ (l & 7)) << 4);
      bf16x8 a[4], b[4];
#pragma unroll
      for (int m = 0; m < 4; m++)
        a[m] = *(const bf16x8*)(As_ + (arow + m * 16) * 128 + cx);
#pragma unroll
      for (int n = 0; n < 4; n++)
        b[n] = *(const bf16x8*)(Bs_ + (brw + n * 16) * 128 + cx);
#pragma unroll
      for (int m = 0; m < 4; m++)
#pragma unroll
        for (int n = 0; n < 4; n++)
          acc[m][n] = __builtin_amdgcn_mfma_f32_16x16x32_bf16(a[m], b[n], acc[m][n], 0, 0, 0);
    }
  };

  stage(A0, B0, 0);
  __syncthreads();
  for (int kt = 0; kt < nkt; kt += 2) {
    stage(A1, B1, kt + 1);       // prefetch odd tile
    compute(A0, B0);
    __syncthreads();             // drain prefetch AFTER compute
    if (kt + 2 < nkt) stage(A0, B0, kt + 2);
    compute(A1, B1);
    __syncthreads();
  }
}

// Write acc (bf16 values) into LDS 128x128 tile-local layout.
__device__ __forceinline__ void acc_to_lds_bf16(f32x4 (&acc)[4][4], ushort* smem) {
  const int tid = threadIdx.x, w = tid >> 6, l = tid & 63;
  const int r0l = ((w >> 1) << 6) + ((l >> 4) << 2);
  const int c0l = ((w & 1) << 6) + (l & 15);
#pragma unroll
  for (int n = 0; n < 4; n++)
#pragma unroll
    for (int m = 0; m < 4; m++)
#pragma unroll
      for (int j = 0; j < 4; j++)
        smem[(r0l + m * 16 + j) * 128 + (c0l + n * 16)] = f2b(acc[m][n][j]);
}

// ---------------- kernels ----------------

__global__ __launch_bounds__(256) void k_cvt(const float* __restrict__ in,
                                             ushort* __restrict__ out) {
  const long i = ((long)blockIdx.x * 256 + threadIdx.x) << 2;
  const float4 v = *(const float4*)(in + i);
  ushort4 o;
  o.x = f2b(v.x); o.y = f2b(v.y); o.z = f2b(v.z); o.w = f2b(v.w);
  *(ushort4*)(out + i) = o;
}

__device__ __forceinline__ float ld2f(const float* p, long i) { return p[i]; }
__device__ __forceinline__ float ld2f(const __hip_bfloat16* p, long i) { return __bfloat162float(p[i]); }

template <typename TIN>
__global__ __launch_bounds__(256) void k_tr(const TIN* __restrict__ in, ushort* __restrict__ out,
                                            int R, int C, long inB, long outB) {
  __shared__ float t[32][33];
  const long b = blockIdx.z;
  const TIN* ip = in + b * inB;
  ushort* op = out + b * outB;
  const int c0 = blockIdx.x << 5, r0 = blockIdx.y << 5;
  const int tx = threadIdx.x & 31, ty = threadIdx.x >> 5;
#pragma unroll
  for (int j = 0; j < 32; j += 8)
    t[ty + j][tx] = ld2f(ip, (long)(r0 + ty + j) * C + (c0 + tx));
  __syncthreads();
#pragma unroll
  for (int j = 0; j < 32; j += 8)
    op[(long)(c0 + ty + j) * R + (r0 + tx)] = f2b(t[tx][ty + j]);
}

__global__ __launch_bounds__(256) void k_gemm1(const ushort* __restrict__ xb,
                                               const ushort* __restrict__ w1t,
                                               const float* __restrict__ b1,
                                               ushort* __restrict__ hb) {
  __shared__ ushort smem[128 * 256];
  f32x4 acc[4][4];
  const int brow = blockIdx.x << 7, bcol = blockIdx.y << 7;
  gemm_core_128(xb, w1t, DM, brow, bcol, acc, smem);
  const int tid = threadIdx.x, w = tid >> 6, l = tid & 63;
  const int c0l = ((w & 1) << 6) + (l & 15);
#pragma unroll
  for (int n = 0; n < 4; n++) {
    const float bias = b1[bcol + c0l + n * 16];
#pragma unroll
    for (int m = 0; m < 4; m++)
#pragma unroll
      for (int j = 0; j < 4; j++) {
        float v = acc[m][n][j] + bias;
        acc[m][n][j] = v > 0.f ? v : 0.f;
      }
  }
  acc_to_lds_bf16(acc, smem);
  __syncthreads();
  const int rb = tid >> 4, cb = tid & 15;
#pragma unroll
  for (int i = 0; i < 8; i++) {
    const int row = i * 16 + rb;
    bf16x8 s = *(const bf16x8*)(smem + row * 128 + cb * 8);
    *(bf16x8*)(hb + (long)(brow + row) * DF + bcol + cb * 8) = s;
  }
}

__global__ __launch_bounds__(256) void k_gemm2(const ushort* __restrict__ hb,
                                               const ushort* __restrict__ w2t,
                                               const float* __restrict__ b2,
                                               ushort* __restrict__ kb,
                                               ushort* __restrict__ qb,
                                               ushort* __restrict__ vb) {
  __shared__ ushort smem[128 * 256];
  f32x4 acc[4][4];
  const int brow = blockIdx.x << 7, bcol = blockIdx.y << 7;
  gemm_core_128(hb, w2t, DF, brow, bcol, acc, smem);
  const int seg = bcol >> 9;  // 0:k 1:q 2:v
  ushort* dst = (seg == 0) ? kb : ((seg == 1) ? qb : vb);
  const float sc = (seg == 1) ? 0.04419417382415922f : 1.0f;  // 1/sqrt(512) into q
  const int tid = threadIdx.x, w = tid >> 6, l = tid & 63;
  const int c0l = ((w & 1) << 6) + (l & 15);
#pragma unroll
  for (int n = 0; n < 4; n++) {
    const float bias = b2[bcol + c0l + n * 16];
#pragma unroll
    for (int m = 0; m < 4; m++)
#pragma unroll
      for (int j = 0; j < 4; j++)
        acc[m][n][j] = (acc[m][n][j] + bias) * sc;
  }
  acc_to_lds_bf16(acc, smem);
  __syncthreads();
  const int rb = tid >> 4, cb = tid & 15;
  const int clb = bcol - (seg << 9);
#pragma unroll
  for (int i = 0; i < 8; i++) {
    const int row = i * 16 + rb;
    bf16x8 s = *(const bf16x8*)(smem + row * 128 + cb * 8);
    *(bf16x8*)(dst + (long)(brow + row) * DM + clb + cb * 8) = s;
  }
}

// qk: 1-D grid (2048) with T1 XCD swizzle -> each batch pinned to one XCD.
// Mask prefetched to registers at start (hidden under the K-loop).
__global__ __launch_bounds__(256) void k_qk(const ushort* __restrict__ qb,
                                            const ushort* __restrict__ kb,
                                            const float* __restrict__ mask,
                                            ushort* __restrict__ Sbuf) {
  __shared__ ushort smem[128 * 256];
  const int orig = blockIdx.x;
  const int swz = (orig & 7) * 256 + (orig >> 3);  // nwg=2048, bijective
  const int bx = swz & 15, by = (swz >> 4) & 15, batch = swz >> 8;
  const int brow = bx << 7, bcol = by << 7;
  const ushort* A = qb + (long)batch * NN * DM;
  const ushort* Bm = kb + (long)batch * NN * DM;
  const float* mk = mask + (long)batch * NN * NN;
  ushort* S = Sbuf + (long)batch * NN * NN;

  // prefetch mask tile slice into regs (coalesced float4 pairs)
  const int tid = threadIdx.x, rb = tid >> 4, cb = tid & 15;
  float4 mreg[8][2];
#pragma unroll
  for (int i = 0; i < 8; i++) {
    const long goff = (long)(brow + i * 16 + rb) * NN + bcol + cb * 8;
    mreg[i][0] = *(const float4*)(mk + goff);
    mreg[i][1] = *(const float4*)(mk + goff + 4);
  }

  f32x4 acc[4][4];
  gemm_core_128(A, Bm, DM, brow, bcol, acc, smem);
  acc_to_lds_bf16(acc, smem);
  __syncthreads();
#pragma unroll
  for (int i = 0; i < 8; i++) {
    const int row = i * 16 + rb;
    const long goff = (long)(brow + row) * NN + bcol + cb * 8;
    bf16x8 s = *(const bf16x8*)(smem + row * 128 + cb * 8);
    bf16x8 o;
    o[0] = (short)f2b(b2f((ushort)s[0]) * mreg[i][0].x);
    o[1] = (short)f2b(b2f((ushort)s[1]) * mreg[i][0].y);
    o[2] = (short)f2b(b2f((ushort)s[2]) * mreg[i][0].z);
    o[3] = (short)f2b(b2f((ushort)s[3]) * mreg[i][0].w);
    o[4] = (short)f2b(b2f((ushort)s[4]) * mreg[i][1].x);
    o[5] = (short)f2b(b2f((ushort)s[5]) * mreg[i][1].y);
    o[6] = (short)f2b(b2f((ushort)s[6]) * mreg[i][1].z);
    o[7] = (short)f2b(b2f((ushort)s[7]) * mreg[i][1].w);
    *(bf16x8*)(S + goff) = o;
  }
}

__global__ __launch_bounds__(256) void k_pv(const ushort* __restrict__ Sbuf,
                                            const ushort* __restrict__ vtb,
                                            float* __restrict__ out) {
  __shared__ ushort smem[128 * 256];
  const int batch = blockIdx.z;
  const ushort* A = Sbuf + (long)batch * NN * NN;
  const ushort* Bm = vtb + (long)batch * DM * NN;  // v^T [512][2048]
  float* op = out + (long)batch * NN * DM;
  f32x4 acc[4][4];
  const int brow = blockIdx.x << 7, bcol = blockIdx.y << 7;
  gemm_core_128(A, Bm, NN, brow, bcol, acc, smem);
  const int tid = threadIdx.x, w = tid >> 6, l = tid & 63;
  const int r0 = brow + ((w >> 1) << 6) + ((l >> 4) << 2);
  const int c0 = bcol + ((w & 1) << 6) + (l & 15);
#pragma unroll
  for (int n = 0; n < 4; n++) {
    const int c = c0 + n * 16;
#pragma unroll
    for (int m = 0; m < 4; m++) {
      const int r = r0 + m * 16;
#pragma unroll
      for (int j = 0; j < 4; j++)
        op[(long)(r + j) * DM + c] = acc[m][n][j];
    }
  }
}

// ---------------- launch ----------------
extern "C" void kernel_launch(void* const* d_in, const int* in_sizes, int n_in,
                              void* d_out, int out_size, void* d_ws, size_t ws_size,
                              hipStream_t stream) {
  const float* x    = (const float*)d_in[0];
  const float* mask = (const float*)d_in[1];
  const float* W1   = (const float*)d_in[2];
  const float* b1   = (const float*)d_in[3];
  const float* W2   = (const float*)d_in[4];
  const float* b2   = (const float*)d_in[5];
  float* out = (float*)d_out;

  char* ws = (char*)d_ws;
  size_t off = 0;
  auto alloc = [&](size_t n) { char* p = ws + off; off += (n + 255) & ~(size_t)255; return p; };
  ushort* xb  = (ushort*)alloc((size_t)NB * NN * DM * 2);
  ushort* hb  = (ushort*)alloc((size_t)NB * NN * DF * 2);
  ushort* w1t = (ushort*)alloc((size_t)DF * DM * 2);
  ushort* w2t = (ushort*)alloc((size_t)3 * DM * DF * 2);
  ushort* kb  = (ushort*)alloc((size_t)NB * NN * DM * 2);
  ushort* qb  = (ushort*)alloc((size_t)NB * NN * DM * 2);
  ushort* vb  = (ushort*)alloc((size_t)NB * NN * DM * 2);
  ushort* vtb = (ushort*)alloc((size_t)NB * NN * DM * 2);
  ushort* Sbuf = (ushort*)alloc((size_t)NB * NN * NN * 2);  // 67MB

  // x -> bf16
  k_cvt<<<dim3(8192), dim3(256), 0, stream>>>(x, xb);
  // W1 -> w1t ; W2 -> w2t
  k_tr<float><<<dim3(DF / 32, DM / 32, 1), dim3(256), 0, stream>>>(W1, w1t, DM, DF, 0, 0);
  k_tr<float><<<dim3(3 * DM / 32, DF / 32, 1), dim3(256), 0, stream>>>(W2, w2t, DF, 3 * DM, 0, 0);
  // h = relu(x@W1+b1)
  k_gemm1<<<dim3(NB * NN / 128, DF / 128), dim3(256), 0, stream>>>(xb, w1t, b1, hb);
  // kqv = h@W2+b2 (q pre-scaled)
  k_gemm2<<<dim3(NB * NN / 128, 3 * DM / 128), dim3(256), 0, stream>>>(hb, w2t, b2, kb, qb, vb);
  // v -> v^T per batch
  k_tr<__hip_bfloat16><<<dim3(DM / 32, NN / 32, NB), dim3(256), 0, stream>>>(
      (const __hip_bfloat16*)vb, vtb, NN, DM, (long)NN * DM, (long)DM * NN);
  // attention (split, S materialized in bf16)
  k_qk<<<dim3(2048), dim3(256), 0, stream>>>(qb, kb, mask, Sbuf);
  k_pv<<<dim3(NN / 128, DM / 128, NB), dim3(256), 0, stream>>>(Sbuf, vtb, out);
}